// Round 1
// baseline (2225.364 us; speedup 1.0000x reference)
//
#include <hip/hip_runtime.h>

// AdjointODE: h += dt * ( tanh(h@W1+b1) @ W2 + b2 ), 50 Euler steps.
// BATCH=32768, DIM=128, HID=256.
// ROUND 10: DEPTH-2 SOFTWARE PIPELINE of the p-loop (was unroll-1).
// Evidence: MfmaUtil 33 / VALUBusy 57 / Occupancy 21 (grid-capped at
// 2 waves/SIMD) -> latency-bound. unroll-1 serialized the per-p chain
// mm1(4-deep MFMA) -> act(2 trans deep) -> mm2 on the critical path.
// Now stage pp issues: mm1(pp) | act(pp-1) | mm2(pp-2), fully unrolled,
// so every consumer trails its producer by a full iteration and the
// scheduler interleaves trans ops between independent MFMA issues.
// VGPR headroom is real: occupancy is grid-capped, so budget is 256/lane
// (was using 88). Spill canary: FETCH_SIZE must stay ~9.3 MB.
// Everything else = r9: fragment-linear weight LDS (conflict-free b128
// staging + reads, offsets fold to immediates), 256x512, wave owns 16
// rows, h fp32-resident, sigma-matched pure-register pk2 packing, b1 as
// accumulator init (TSCALE-folded), b2 via VALU fma. Step loop unroll-1.

typedef __attribute__((ext_vector_type(8))) short short8;
typedef __attribute__((ext_vector_type(4))) float float4v;
typedef __attribute__((ext_vector_type(4))) int int4v;

union FB { int4v i; short8 s; };

// LDS map (bytes)
#define W1F_OFF 0        // 64 frags (nt*4+c) x 1 KB = 64 KB
#define W2F_OFF 65536    // 64 frags (p*8+tb) x 1 KB = 64 KB
#define B1_OFF  131072   // f32[256] (TSCALE-folded b1)
#define DT_OFF  132096   // f32[64]
#define LDS_BYTES 132352

#define TSCALE 2.8853900817779268f  // 2/ln2: tanh(x) = 1 - 2/(exp2(x*TSCALE)+1)

__device__ __forceinline__ unsigned rne2(float x) {
  unsigned u = __float_as_uint(x);
  return u + 0x7fffu + ((u >> 16) & 1u);
}

#if __has_builtin(__builtin_amdgcn_cvt_pk_bf16_f32)
__device__ __forceinline__ int pk2(float lo, float hi) {
  return __builtin_bit_cast(int, __builtin_amdgcn_cvt_pk_bf16_f32(lo, hi));
}
#else
__device__ __forceinline__ int pk2(float lo, float hi) {
  return (int)__builtin_amdgcn_perm(rne2(hi), rne2(lo), 0x07060302u);
}
#endif

// B-frag for one 32-K chunk from two C-layout float4 tiles (even, odd).
__device__ __forceinline__ int4v packfrag(float4v e, float4v o) {
  int4v f;
  f.x = pk2(e.x, e.y);
  f.y = pk2(e.z, e.w);
  f.z = pk2(o.x, o.y);
  f.w = pk2(o.z, o.w);
  return f;
}

#define MFMA16(a, b, c) __builtin_amdgcn_mfma_f32_16x16x32_bf16(a, b, c, 0, 0, 0)

extern "C" __global__ __launch_bounds__(512)
void ode_kernel(const float* __restrict__ inp, const float* __restrict__ ts,
                const float* __restrict__ W1, const float* __restrict__ b1,
                const float* __restrict__ W2, const float* __restrict__ b2,
                float* __restrict__ out) {
  __shared__ __align__(16) char ldsb[LDS_BYTES];
  float* b1f = (float*)(ldsb + B1_OFF);
  float* dtf = (float*)(ldsb + DT_OFF);

  const int tid = threadIdx.x;
  const int lane = tid & 63, wave = tid >> 6;
  const int ln = lane & 15;  // batch-row within wave's 16
  const int q = lane >> 4;   // quad
  const int row = blockIdx.x * 128 + wave * 16 + ln;

  // ---- stage W1 frags: pair pi = (fid=nt*4+c)*64 + L; wave covers one frag ----
  #pragma unroll 1
  for (int it = 0; it < 8; it++) {
    const int pi = it * 512 + tid;  // [0, 4096)
    const int fid = pi >> 6, L = pi & 63;
    const int nt = fid >> 2, c = fid & 3;
    const int lf = L & 15, qf = L >> 4;
    const int n = nt * 16 + lf;            // hid index (A-frag m-row)
    const int kb = c * 32 + qf * 4;        // logical dim base
    float v0 = W1[(kb + 0) * 256 + n] * TSCALE;
    float v1 = W1[(kb + 1) * 256 + n] * TSCALE;
    float v2 = W1[(kb + 2) * 256 + n] * TSCALE;
    float v3 = W1[(kb + 3) * 256 + n] * TSCALE;
    float v4 = W1[(kb + 16) * 256 + n] * TSCALE;
    float v5 = W1[(kb + 17) * 256 + n] * TSCALE;
    float v6 = W1[(kb + 18) * 256 + n] * TSCALE;
    float v7 = W1[(kb + 19) * 256 + n] * TSCALE;
    int4v d = {pk2(v0, v1), pk2(v2, v3), pk2(v4, v5), pk2(v6, v7)};
    *(int4v*)(ldsb + W1F_OFF + pi * 16) = d;
  }
  // ---- stage W2 frags: fid = p*8 + tb ----
  #pragma unroll 1
  for (int it = 0; it < 8; it++) {
    const int pi = it * 512 + tid;
    const int fid = pi >> 6, L = pi & 63;
    const int p = fid >> 3, tb = fid & 7;
    const int lf = L & 15, qf = L >> 4;
    const int d_out = tb * 16 + lf;        // output-dim (A-frag m-row)
    const int kb = p * 32 + qf * 4;        // logical hid base
    float v0 = W2[(kb + 0) * 128 + d_out];
    float v1 = W2[(kb + 1) * 128 + d_out];
    float v2 = W2[(kb + 2) * 128 + d_out];
    float v3 = W2[(kb + 3) * 128 + d_out];
    float v4 = W2[(kb + 16) * 128 + d_out];
    float v5 = W2[(kb + 17) * 128 + d_out];
    float v6 = W2[(kb + 18) * 128 + d_out];
    float v7 = W2[(kb + 19) * 128 + d_out];
    int4v d = {pk2(v0, v1), pk2(v2, v3), pk2(v4, v5), pk2(v6, v7)};
    *(int4v*)(ldsb + W2F_OFF + pi * 16) = d;
  }
  if (tid < 256) b1f[tid] = b1[tid] * TSCALE;
  if (tid < 50) dtf[tid] = ts[tid + 1] - ts[tid];

  // ---- b2 resident per-lane (C-layout columns) ----
  float4v b2v[8];
  #pragma unroll
  for (int tb = 0; tb < 8; tb++)
    b2v[tb] = *(const float4v*)&b2[tb * 16 + q * 4];

  // ---- load h: 16x16 C-layout. h4[tb][r] = h[row][tb*16 + q*4 + r] ----
  float4v h4[8];
  #pragma unroll
  for (int tb = 0; tb < 8; tb++)
    h4[tb] = *(const float4v*)&inp[row * 128 + tb * 16 + q * 4];

  __syncthreads();  // the only barrier

  // per-lane frag base pointers (reads: base + fid*64 int4vs + immediate)
  const int4v* w1f = (const int4v*)(ldsb + W1F_OFF) + lane;
  const int4v* w2f = (const int4v*)(ldsb + W2F_OFF) + lane;

  #pragma unroll 1
  for (int s = 0; s < 50; s++) {
    const float dt = dtf[s];
    const float m2dt = -2.0f * dt;

    // ---- state -> 4 B-frags (pure register packing) ----
    FB hb[4];
    #pragma unroll
    for (int kc = 0; kc < 4; kc++)
      hb[kc].i = packfrag(h4[2 * kc], h4[2 * kc + 1]);

    // ---- depth-2 software pipeline over the 8 hid-pair chunks ----
    // stage pp: mm1(pp) | act(pp-1) | mm2(pp-2). Fully unrolled: all
    // array indices static (no scratch), all LDS offsets immediate.
    float4v g0[8], g1[8];
    FB af[8];
    #pragma unroll
    for (int pp = 0; pp < 10; pp++) {
      // ---- STAGE A: mm1 for chunk p = pp ----
      if (pp < 8) {
        const int p = pp;
        const int nt0 = 2 * p, nt1 = 2 * p + 1;
        FB wA[4], wB[4];
        #pragma unroll
        for (int c = 0; c < 4; c++) {
          wA[c].i = w1f[(nt0 * 4 + c) * 64];
          wB[c].i = w1f[(nt1 * 4 + c) * 64];
        }
        // g init = b1 (pre-scaled), two independent 4-chains
        g0[p] = *(const float4v*)&b1f[nt0 * 16 + q * 4];
        g1[p] = *(const float4v*)&b1f[nt1 * 16 + q * 4];
        #pragma unroll
        for (int c = 0; c < 4; c++) {
          g0[p] = MFMA16(wA[c].s, hb[c].s, g0[p]);
          g1[p] = MFMA16(wB[c].s, hb[c].s, g1[p]);
        }
      }
      // ---- STAGE B: act for chunk p = pp-1 (g ready for a full stage) ----
      if (pp >= 1 && pp <= 8) {
        const int p = pp - 1;
        float4v a0, a1;
        #pragma unroll
        for (int r = 0; r < 4; r++) {
          a0[r] = fmaf(__builtin_amdgcn_rcpf(__builtin_amdgcn_exp2f(g0[p][r]) + 1.0f), m2dt, dt);
          a1[r] = fmaf(__builtin_amdgcn_rcpf(__builtin_amdgcn_exp2f(g1[p][r]) + 1.0f), m2dt, dt);
        }
        af[p].i = packfrag(a0, a1);
      }
      // ---- STAGE C: mm2 for chunk p = pp-2 (af ready for a full stage) ----
      if (pp >= 2) {
        const int p = pp - 2;
        FB w2r[8];
        #pragma unroll
        for (int tb = 0; tb < 8; tb++)
          w2r[tb].i = w2f[(p * 8 + tb) * 64];
        #pragma unroll
        for (int tb = 0; tb < 8; tb++)
          h4[tb] = MFMA16(w2r[tb].s, af[p].s, h4[tb]);
      }
    }

    // ---- h += dt * b2 ----
    #pragma unroll
    for (int tb = 0; tb < 8; tb++)
      #pragma unroll
      for (int r = 0; r < 4; r++)
        h4[tb][r] = fmaf(dt, b2v[tb][r], h4[tb][r]);
  }

  // ---- store ----
  #pragma unroll
  for (int tb = 0; tb < 8; tb++)
    *(float4v*)&out[row * 128 + tb * 16 + q * 4] = h4[tb];
}

extern "C" void kernel_launch(void* const* d_in, const int* in_sizes, int n_in,
                              void* d_out, int out_size, void* d_ws, size_t ws_size,
                              hipStream_t stream) {
  const float* inp = (const float*)d_in[0];
  const float* ts  = (const float*)d_in[1];
  const float* W1  = (const float*)d_in[2];
  const float* b1  = (const float*)d_in[3];
  const float* W2  = (const float*)d_in[4];
  const float* b2  = (const float*)d_in[5];
  hipLaunchKernelGGL(ode_kernel, dim3(256), dim3(512), 0, stream,
                     inp, ts, W1, b1, W2, b2, (float*)d_out);
}

// Round 2
// 310.360 us; speedup vs baseline: 7.1703x; 7.1703x over previous
//
#include <hip/hip_runtime.h>

// AdjointODE: h += dt * ( tanh(h@W1+b1) @ W2 + b2 ), 50 Euler steps.
// BATCH=32768, DIM=128, HID=256.
// ROUND 11: DEPTH-1 ROTATED PIPELINE + EXPLICIT VGPR BUDGET.
// r10 post-mortem: depth-2 pipeline with g0[8]/g1[8]/af[8] arrays needed
// ~+96 VGPR, but __launch_bounds__(512) let the compiler cap at 128 ->
// massive scratch spill (FETCH 9.3MB->5.4GB, MfmaUtil 3%). Fix:
//  (a) __launch_bounds__(512, 2): we are grid-pinned to 2 waves/SIMD
//      anyway (LDS 132KB = 1 block/CU, 8 waves), so declare it and get
//      the 256-VGPR budget;
//  (b) rotation by SCALARS, depth 1: per p: mm1(p) ; mm2(p-1) ; act(p).
//      act(p) hides under next mm1's 8 MFMAs, mm1's accumulator latency
//      hides under mm2's 8 MFMAs, af pack latency hides under next mm1.
//      Only one (g0,g1) + one af live: +12 VGPRs, not +96.
// p-loop stays unroll-1 (runtime loop; rotation needs no arrays).
// Spill canary: FETCH ~9.3 MB / WRITE 16 MB. VGPR must read < 256.
// Everything else = r9: fragment-linear weight LDS (conflict-free b128
// staging + reads, offsets fold to immediates), 256x512, wave owns 16
// rows, h fp32-resident, sigma-matched pure-register pk2 packing, b1 as
// accumulator init (TSCALE-folded), b2 via VALU fma.

typedef __attribute__((ext_vector_type(8))) short short8;
typedef __attribute__((ext_vector_type(4))) float float4v;
typedef __attribute__((ext_vector_type(4))) int int4v;

union FB { int4v i; short8 s; };

// LDS map (bytes)
#define W1F_OFF 0        // 64 frags (nt*4+c) x 1 KB = 64 KB
#define W2F_OFF 65536    // 64 frags (p*8+tb) x 1 KB = 64 KB
#define B1_OFF  131072   // f32[256] (TSCALE-folded b1)
#define DT_OFF  132096   // f32[64]
#define LDS_BYTES 132352

#define TSCALE 2.8853900817779268f  // 2/ln2: tanh(x) = 1 - 2/(exp2(x*TSCALE)+1)

__device__ __forceinline__ unsigned rne2(float x) {
  unsigned u = __float_as_uint(x);
  return u + 0x7fffu + ((u >> 16) & 1u);
}

#if __has_builtin(__builtin_amdgcn_cvt_pk_bf16_f32)
__device__ __forceinline__ int pk2(float lo, float hi) {
  return __builtin_bit_cast(int, __builtin_amdgcn_cvt_pk_bf16_f32(lo, hi));
}
#else
__device__ __forceinline__ int pk2(float lo, float hi) {
  return (int)__builtin_amdgcn_perm(rne2(hi), rne2(lo), 0x07060302u);
}
#endif

// B-frag for one 32-K chunk from two C-layout float4 tiles (even, odd).
__device__ __forceinline__ int4v packfrag(float4v e, float4v o) {
  int4v f;
  f.x = pk2(e.x, e.y);
  f.y = pk2(e.z, e.w);
  f.z = pk2(o.x, o.y);
  f.w = pk2(o.z, o.w);
  return f;
}

#define MFMA16(a, b, c) __builtin_amdgcn_mfma_f32_16x16x32_bf16(a, b, c, 0, 0, 0)

extern "C" __global__ __launch_bounds__(512, 2)
void ode_kernel(const float* __restrict__ inp, const float* __restrict__ ts,
                const float* __restrict__ W1, const float* __restrict__ b1,
                const float* __restrict__ W2, const float* __restrict__ b2,
                float* __restrict__ out) {
  __shared__ __align__(16) char ldsb[LDS_BYTES];
  float* b1f = (float*)(ldsb + B1_OFF);
  float* dtf = (float*)(ldsb + DT_OFF);

  const int tid = threadIdx.x;
  const int lane = tid & 63, wave = tid >> 6;
  const int ln = lane & 15;  // batch-row within wave's 16
  const int q = lane >> 4;   // quad
  const int row = blockIdx.x * 128 + wave * 16 + ln;

  // ---- stage W1 frags: pair pi = (fid=nt*4+c)*64 + L; wave covers one frag ----
  #pragma unroll 1
  for (int it = 0; it < 8; it++) {
    const int pi = it * 512 + tid;  // [0, 4096)
    const int fid = pi >> 6, L = pi & 63;
    const int nt = fid >> 2, c = fid & 3;
    const int lf = L & 15, qf = L >> 4;
    const int n = nt * 16 + lf;            // hid index (A-frag m-row)
    const int kb = c * 32 + qf * 4;        // logical dim base
    float v0 = W1[(kb + 0) * 256 + n] * TSCALE;
    float v1 = W1[(kb + 1) * 256 + n] * TSCALE;
    float v2 = W1[(kb + 2) * 256 + n] * TSCALE;
    float v3 = W1[(kb + 3) * 256 + n] * TSCALE;
    float v4 = W1[(kb + 16) * 256 + n] * TSCALE;
    float v5 = W1[(kb + 17) * 256 + n] * TSCALE;
    float v6 = W1[(kb + 18) * 256 + n] * TSCALE;
    float v7 = W1[(kb + 19) * 256 + n] * TSCALE;
    int4v d = {pk2(v0, v1), pk2(v2, v3), pk2(v4, v5), pk2(v6, v7)};
    *(int4v*)(ldsb + W1F_OFF + pi * 16) = d;
  }
  // ---- stage W2 frags: fid = p*8 + tb ----
  #pragma unroll 1
  for (int it = 0; it < 8; it++) {
    const int pi = it * 512 + tid;
    const int fid = pi >> 6, L = pi & 63;
    const int p = fid >> 3, tb = fid & 7;
    const int lf = L & 15, qf = L >> 4;
    const int d_out = tb * 16 + lf;        // output-dim (A-frag m-row)
    const int kb = p * 32 + qf * 4;        // logical hid base
    float v0 = W2[(kb + 0) * 128 + d_out];
    float v1 = W2[(kb + 1) * 128 + d_out];
    float v2 = W2[(kb + 2) * 128 + d_out];
    float v3 = W2[(kb + 3) * 128 + d_out];
    float v4 = W2[(kb + 16) * 128 + d_out];
    float v5 = W2[(kb + 17) * 128 + d_out];
    float v6 = W2[(kb + 18) * 128 + d_out];
    float v7 = W2[(kb + 19) * 128 + d_out];
    int4v d = {pk2(v0, v1), pk2(v2, v3), pk2(v4, v5), pk2(v6, v7)};
    *(int4v*)(ldsb + W2F_OFF + pi * 16) = d;
  }
  if (tid < 256) b1f[tid] = b1[tid] * TSCALE;
  if (tid < 50) dtf[tid] = ts[tid + 1] - ts[tid];

  // ---- b2 resident per-lane (C-layout columns) ----
  float4v b2v[8];
  #pragma unroll
  for (int tb = 0; tb < 8; tb++)
    b2v[tb] = *(const float4v*)&b2[tb * 16 + q * 4];

  // ---- load h: 16x16 C-layout. h4[tb][r] = h[row][tb*16 + q*4 + r] ----
  float4v h4[8];
  #pragma unroll
  for (int tb = 0; tb < 8; tb++)
    h4[tb] = *(const float4v*)&inp[row * 128 + tb * 16 + q * 4];

  __syncthreads();  // the only barrier

  // per-lane frag base pointers (reads: base + fid*64 int4vs + immediate)
  const int4v* w1f = (const int4v*)(ldsb + W1F_OFF) + lane;
  const int4v* w2f = (const int4v*)(ldsb + W2F_OFF) + lane;

  #pragma unroll 1
  for (int s = 0; s < 50; s++) {
    const float dt = dtf[s];
    const float m2dt = -2.0f * dt;

    // ---- state -> 4 B-frags (pure register packing) ----
    FB hb[4];
    #pragma unroll
    for (int kc = 0; kc < 4; kc++)
      hb[kc].i = packfrag(h4[2 * kc], h4[2 * kc + 1]);

    // ---- rotated depth-1 pipeline over 8 hid-pair chunks ----
    // prologue: mm1(0) + act(0) -> af (trans latency exposed once/step)
    FB af;
    {
      FB wA[4], wB[4];
      #pragma unroll
      for (int c = 0; c < 4; c++) {
        wA[c].i = w1f[(0 * 4 + c) * 64];
        wB[c].i = w1f[(1 * 4 + c) * 64];
      }
      float4v g0 = *(const float4v*)&b1f[0 * 16 + q * 4];
      float4v g1 = *(const float4v*)&b1f[1 * 16 + q * 4];
      #pragma unroll
      for (int c = 0; c < 4; c++) {
        g0 = MFMA16(wA[c].s, hb[c].s, g0);
        g1 = MFMA16(wB[c].s, hb[c].s, g1);
      }
      float4v a0, a1;
      #pragma unroll
      for (int r = 0; r < 4; r++) {
        a0[r] = fmaf(__builtin_amdgcn_rcpf(__builtin_amdgcn_exp2f(g0[r]) + 1.0f), m2dt, dt);
        a1[r] = fmaf(__builtin_amdgcn_rcpf(__builtin_amdgcn_exp2f(g1[r]) + 1.0f), m2dt, dt);
      }
      af.i = packfrag(a0, a1);
    }

    // steady state: per p issue mm1(p) ; mm2(p-1) ; act(p).
    //  - mm2(p-1) reads af BEFORE act(p) overwrites it (reg rotation)
    //  - act(p)'s trans chain drains under the NEXT iteration's mm1
    //  - mm1(p)'s accumulator latency drains under mm2(p-1)'s 8 MFMAs
    #pragma unroll 1
    for (int p = 1; p < 8; p++) {
      const int nt0 = 2 * p, nt1 = 2 * p + 1;
      // mm1(p)
      FB wA[4], wB[4];
      #pragma unroll
      for (int c = 0; c < 4; c++) {
        wA[c].i = w1f[(nt0 * 4 + c) * 64];
        wB[c].i = w1f[(nt1 * 4 + c) * 64];
      }
      float4v g0 = *(const float4v*)&b1f[nt0 * 16 + q * 4];
      float4v g1 = *(const float4v*)&b1f[nt1 * 16 + q * 4];
      #pragma unroll
      for (int c = 0; c < 4; c++) {
        g0 = MFMA16(wA[c].s, hb[c].s, g0);
        g1 = MFMA16(wB[c].s, hb[c].s, g1);
      }
      // mm2(p-1): consumes af from previous iteration
      {
        FB w2r[8];
        #pragma unroll
        for (int tb = 0; tb < 8; tb++)
          w2r[tb].i = w2f[((p - 1) * 8 + tb) * 64];
        #pragma unroll
        for (int tb = 0; tb < 8; tb++)
          h4[tb] = MFMA16(w2r[tb].s, af.s, h4[tb]);
      }
      // act(p): refill af for next iteration (or epilogue)
      float4v a0, a1;
      #pragma unroll
      for (int r = 0; r < 4; r++) {
        a0[r] = fmaf(__builtin_amdgcn_rcpf(__builtin_amdgcn_exp2f(g0[r]) + 1.0f), m2dt, dt);
        a1[r] = fmaf(__builtin_amdgcn_rcpf(__builtin_amdgcn_exp2f(g1[r]) + 1.0f), m2dt, dt);
      }
      af.i = packfrag(a0, a1);
    }

    // epilogue: mm2(7)
    {
      FB w2r[8];
      #pragma unroll
      for (int tb = 0; tb < 8; tb++)
        w2r[tb].i = w2f[(7 * 8 + tb) * 64];
      #pragma unroll
      for (int tb = 0; tb < 8; tb++)
        h4[tb] = MFMA16(w2r[tb].s, af.s, h4[tb]);
    }

    // ---- h += dt * b2 ----
    #pragma unroll
    for (int tb = 0; tb < 8; tb++)
      #pragma unroll
      for (int r = 0; r < 4; r++)
        h4[tb][r] = fmaf(dt, b2v[tb][r], h4[tb][r]);
  }

  // ---- store ----
  #pragma unroll
  for (int tb = 0; tb < 8; tb++)
    *(float4v*)&out[row * 128 + tb * 16 + q * 4] = h4[tb];
}

extern "C" void kernel_launch(void* const* d_in, const int* in_sizes, int n_in,
                              void* d_out, int out_size, void* d_ws, size_t ws_size,
                              hipStream_t stream) {
  const float* inp = (const float*)d_in[0];
  const float* ts  = (const float*)d_in[1];
  const float* W1  = (const float*)d_in[2];
  const float* b1  = (const float*)d_in[3];
  const float* W2  = (const float*)d_in[4];
  const float* b2  = (const float*)d_in[5];
  hipLaunchKernelGGL(ode_kernel, dim3(256), dim3(512), 0, stream,
                     inp, ts, W1, b1, W2, b2, (float*)d_out);
}